// Round 9
// baseline (718.260 us; speedup 1.0000x reference)
//
#include <hip/hip_runtime.h>
#include <hip/hip_bf16.h>

// loss = (1/N) * [ sum_i softplus(-s_ii) + sum_{i!=j} softplus(s_ij) ] + ln2
// S = E E^T, N=16384, D=128.
// E pre-scaled by sqrt(log2e) in the bf16 cast -> scores in log2 domain;
// softplus*log2e = max(v,0) + log2(1+2^-|v|), log2(1+u) ~= u*(QC0+QC1*u).
// HYBRID, spill-free: 64x64 tiles, 256 threads (2x2 waves, 32x32/wave,
// acc=16 VGPR). B-tile LDS (16KB, XOR-swizzled); A-fragments from global
// (L2-resident). launch_bounds(256,6): VGPR cap 85 (no spill), 24 waves/CU,
// 6 blocks/CU. Triangular grid 32896 blocks. Per-wave atomics to 64 padded
// buckets + last-block-done final reduction (no separate finalize launch).

#define N_DOCS 16384
#define DIM 128
#define NT 256                     // N_DOCS / 64
#define NTRI (NT * (NT + 1) / 2)   // 32896

typedef __attribute__((ext_vector_type(8))) __bf16 bf16x8;
typedef __attribute__((ext_vector_type(4))) float f32x4;

typedef const __attribute__((address_space(1))) unsigned char* gptr_t;
typedef __attribute__((address_space(3))) unsigned char* lptr_t;

#define SQRT_LOG2E 1.2011224087864498f
#define LN2F 0.6931471805599453f
// log2(1+u) ~= u*(QC0 + QC1*u) on [0,1]
#define QC0 1.33985f
#define QC1 (-0.33985f)

#if __has_builtin(__builtin_amdgcn_exp2f)
#define EXP2F(x) __builtin_amdgcn_exp2f(x)
#else
#define EXP2F(x) exp2f(x)
#endif

#define NBUCKET 64
#define BSTRIDE 16  // floats: 64B-padded buckets

__device__ __forceinline__ unsigned short f2bf(float f) {
  unsigned int u = __float_as_uint(f);
  u += 0x7fffu + ((u >> 16) & 1u);  // round-to-nearest-even
  return (unsigned short)(u >> 16);
}

__global__ void cast_kernel(const float* __restrict__ in, unsigned short* __restrict__ out,
                            float* __restrict__ buckets, unsigned int* __restrict__ counter) {
  int i = blockIdx.x * blockDim.x + threadIdx.x;
  if (blockIdx.x == 0) {
    if (threadIdx.x < NBUCKET) buckets[threadIdx.x * BSTRIDE] = 0.f;
    else if (threadIdx.x == NBUCKET) *counter = 0u;
  }
  float4 v = reinterpret_cast<const float4*>(in)[i];
  ushort4 o;
  o.x = f2bf(v.x * SQRT_LOG2E); o.y = f2bf(v.y * SQRT_LOG2E);
  o.z = f2bf(v.z * SQRT_LOG2E); o.w = f2bf(v.w * SQRT_LOG2E);
  reinterpret_cast<ushort4*>(out)[i] = o;
}

// Swizzle involution: physical LDS byte p holds logical byte p^(((p>>8)&7)<<4);
// read side applies the same XOR (bits 4..6, below the 256B row stride).

template <bool FROM_BF16>
__global__ __launch_bounds__(256, 6) void loss_kernel(const void* __restrict__ src,
                                                      float* __restrict__ buckets,
                                                      unsigned int* __restrict__ counter,
                                                      float* __restrict__ out) {
  // triangular decode: block b -> (tr, tc), tr <= tc, 64-row tiles
  const int b = blockIdx.x;
  int tr = (int)((2 * NT + 1 - sqrtf((float)((2 * NT + 1) * (2 * NT + 1)) - 8.0f * (float)b)) * 0.5f);
  while (tr * NT - tr * (tr - 1) / 2 > b) --tr;
  while ((tr + 1) * NT - (tr + 1) * tr / 2 <= b) ++tr;
  const int tc = tr + (b - (tr * NT - tr * (tr - 1) / 2));

  __shared__ alignas(16) unsigned short Bs[64 * 128];  // 16 KiB
  __shared__ int lastFlag;
  const int tid = threadIdx.x;
  const int wid = tid >> 6;
  const int lane = tid & 63;
  const int wm = wid >> 1, wn = wid & 1;  // 2x2 waves: 32x32 output each
  const int lrow = lane & 15;
  const int kgrp = lane >> 4;

  // ---- stage B tile (64 rows x 256B) into LDS, swizzled ----
  if constexpr (FROM_BF16) {
    const unsigned char* srcB = (const unsigned char*)src + (size_t)tc * 16384;
#pragma unroll
    for (int it = 0; it < 4; ++it) {
      int p = (it * 256 + tid) * 16;
      int g = p ^ (((p >> 8) & 7) << 4);
      __builtin_amdgcn_global_load_lds((gptr_t)(srcB + g),
                                       (lptr_t)((unsigned char*)Bs + p), 16, 0, 0);
    }
  } else {
    const float4* srcB4 = (const float4*)((const float*)src + (size_t)tc * 8192);
#pragma unroll
    for (int it = 0; it < 8; ++it) {
      int idx = it * 256 + tid;  // float4 index within 64x128 slab [0,2048)
      int L = idx * 8;
      int swz = L ^ (((L >> 8) & 7) << 4);
      float4 bb = srcB4[idx];
      ushort4 ob = {f2bf(bb.x * SQRT_LOG2E), f2bf(bb.y * SQRT_LOG2E),
                    f2bf(bb.z * SQRT_LOG2E), f2bf(bb.w * SQRT_LOG2E)};
      *reinterpret_cast<ushort4*>((unsigned char*)Bs + swz) = ob;
    }
  }
  __syncthreads();

  f32x4 acc[2][2];
#pragma unroll
  for (int a = 0; a < 2; ++a)
#pragma unroll
    for (int c = 0; c < 2; ++c) acc[a][c] = (f32x4){0.f, 0.f, 0.f, 0.f};

  // ---- K-loop: A from global (L1/L2), B from LDS ----
  if constexpr (FROM_BF16) {
    const unsigned char* pa = (const unsigned char*)src + (size_t)tr * 16384 +
                              (wm * 32 + lrow) * 256 + kgrp * 16;
#pragma unroll
    for (int ks = 0; ks < 4; ++ks) {
      bf16x8 af[2], bfr[2];
#pragma unroll
      for (int f = 0; f < 2; ++f)
        af[f] = *reinterpret_cast<const bf16x8*>(pa + f * 16 * 256 + ks * 64);
#pragma unroll
      for (int f = 0; f < 2; ++f) {
        int br = wn * 32 + f * 16 + lrow;
        int bb = (br * 256 + ks * 64 + kgrp * 16) ^ ((br & 7) << 4);
        bfr[f] = *reinterpret_cast<const bf16x8*>((const unsigned char*)Bs + bb);
      }
#pragma unroll
      for (int fm = 0; fm < 2; ++fm)
#pragma unroll
        for (int fn = 0; fn < 2; ++fn)
          acc[fm][fn] = __builtin_amdgcn_mfma_f32_16x16x32_bf16(af[fm], bfr[fn], acc[fm][fn], 0, 0, 0);
    }
  } else {
    const float* pa = (const float*)src + (size_t)tr * 8192 + (wm * 32 + lrow) * 128 + kgrp * 8;
#pragma unroll
    for (int ks = 0; ks < 4; ++ks) {
      bf16x8 af[2], bfr[2];
#pragma unroll
      for (int f = 0; f < 2; ++f) {
        float4 lo = *reinterpret_cast<const float4*>(pa + f * 16 * 128 + ks * 32);
        float4 hi = *reinterpret_cast<const float4*>(pa + f * 16 * 128 + ks * 32 + 4);
        ushort4 ulo = {f2bf(lo.x * SQRT_LOG2E), f2bf(lo.y * SQRT_LOG2E),
                       f2bf(lo.z * SQRT_LOG2E), f2bf(lo.w * SQRT_LOG2E)};
        ushort4 uhi = {f2bf(hi.x * SQRT_LOG2E), f2bf(hi.y * SQRT_LOG2E),
                       f2bf(hi.z * SQRT_LOG2E), f2bf(hi.w * SQRT_LOG2E)};
        struct { ushort4 a, b; } pack{ulo, uhi};
        af[f] = *reinterpret_cast<const bf16x8*>(&pack);
      }
#pragma unroll
      for (int f = 0; f < 2; ++f) {
        int br = wn * 32 + f * 16 + lrow;
        int bb = (br * 256 + ks * 64 + kgrp * 16) ^ ((br & 7) << 4);
        bfr[f] = *reinterpret_cast<const bf16x8*>((const unsigned char*)Bs + bb);
      }
#pragma unroll
      for (int fm = 0; fm < 2; ++fm)
#pragma unroll
        for (int fn = 0; fn < 2; ++fn)
          acc[fm][fn] = __builtin_amdgcn_mfma_f32_16x16x32_bf16(af[fm], bfr[fn], acc[fm][fn], 0, 0, 0);
    }
  }

  // ---- epilogue, log2 domain. C/D layout: col=lane&15, row=(lane>>4)*4+reg.
  float sm = 0.f, sp = 0.f;
  if (tr == tc) {
#pragma unroll
    for (int fm = 0; fm < 2; ++fm)
#pragma unroll
      for (int fn = 0; fn < 2; ++fn)
#pragma unroll
        for (int r = 0; r < 4; ++r) {
          float v = acc[fm][fn][r];
          int il = wm * 32 + fm * 16 + kgrp * 4 + r;
          int jl = wn * 32 + fn * 16 + lrow;
          if (il == jl) v = -v;
          sm += fmaxf(v, 0.f);
          float u = EXP2F(-fabsf(v));
          sp = fmaf(u, fmaf(u, QC1, QC0), sp);
        }
  } else {
#pragma unroll
    for (int fm = 0; fm < 2; ++fm)
#pragma unroll
      for (int fn = 0; fn < 2; ++fn)
#pragma unroll
        for (int r = 0; r < 4; ++r) {
          float v = acc[fm][fn][r];
          sm += fmaxf(v, 0.f);
          float u = EXP2F(-fabsf(v));
          sp = fmaf(u, fmaf(u, QC1, QC0), sp);
        }
    sm *= 2.f;  // symmetric twin tile
    sp *= 2.f;
  }

  float lsum = sm + sp;
#pragma unroll
  for (int off = 32; off > 0; off >>= 1) lsum += __shfl_down(lsum, off);
  if (lane == 0)
    atomicAdd(buckets + (((b << 2) + wid) & (NBUCKET - 1)) * BSTRIDE, lsum);

  // ---- last-block-done final reduction (replaces finalize kernel) ----
  __syncthreads();  // drains vmcnt -> this block's bucket atomics complete
  if (tid == 0) {
    __threadfence();
    unsigned int old = atomicAdd(counter, 1u);
    lastFlag = (old == (unsigned int)(NTRI - 1));
  }
  __syncthreads();
  if (lastFlag && tid < NBUCKET) {
    __threadfence();
    float v = atomicAdd(buckets + tid * BSTRIDE, 0.f);  // coherent read
#pragma unroll
    for (int off = 32; off > 0; off >>= 1) v += __shfl_down(v, off);
    if (tid == 0)
      out[0] = LN2F * (v * (1.0f / (float)N_DOCS) + 1.0f);  // accum in log2 units
  }
}

extern "C" void kernel_launch(void* const* d_in, const int* in_sizes, int n_in,
                              void* d_out, int out_size, void* d_ws, size_t ws_size,
                              hipStream_t stream) {
  const float* E = (const float*)d_in[0];
  float* out = (float*)d_out;
  float* buckets = (float*)d_ws;                                    // 4 KiB
  unsigned int* counter = (unsigned int*)((char*)d_ws + 4096);      // 4 B

  const size_t need = 8192 + (size_t)N_DOCS * DIM * sizeof(unsigned short);  // ~4 MiB
  if (ws_size >= need) {
    unsigned short* ebf = (unsigned short*)((char*)d_ws + 8192);
    cast_kernel<<<(N_DOCS * DIM / 4) / 256, 256, 0, stream>>>(E, ebf, buckets, counter);
    loss_kernel<true><<<NTRI, 256, 0, stream>>>(ebf, buckets, counter, out);
  } else {
    (void)hipMemsetAsync(d_ws, 0, 8192, stream);
    loss_kernel<false><<<NTRI, 256, 0, stream>>>(E, buckets, counter, out);
  }
}

// Round 10
// 135.249 us; speedup vs baseline: 5.3106x; 5.3106x over previous
//
#include <hip/hip_runtime.h>
#include <hip/hip_bf16.h>

// loss = (1/N) * [ sum_i softplus(-s_ii) + sum_{i!=j} softplus(s_ij) ] + ln2
// S = E E^T, N=16384, D=128.
// E pre-scaled by sqrt(log2e) in the bf16 cast -> scores in log2 domain;
// softplus*log2e = max(v,0) + log2(1+2^-|v|), log2(1+u) ~= u*(QC0+QC1*u).
// PERSISTENT + PIPELINED (T3 minimum-2-phase): 256 blocks (1/CU, 128KiB LDS),
// each walks ~32 triangular 128x128 tiles with cross-tile double-buffered
// global_load_lds staging, counted s_waitcnt vmcnt(8) (prefetch stays in
// flight across raw s_barrier -- no vmcnt(0) drain), K=128 in LDS, fused
// epilogue, ONE atomicAdd per block at kernel end. No fences/counters (r9
// lesson). K-loop/epilogue/swizzle byte-identical to round 6 (absmax 0.0).

#define N_DOCS 16384
#define DIM 128
#define NTILE 128                      // N_DOCS / 128
#define NTRI (NTILE * (NTILE + 1) / 2) // 8256
#define PBLOCKS 256                    // persistent blocks, 1 per CU

typedef __attribute__((ext_vector_type(8))) __bf16 bf16x8;
typedef __attribute__((ext_vector_type(4))) float f32x4;

typedef const __attribute__((address_space(1))) unsigned char* gptr_t;
typedef __attribute__((address_space(3))) unsigned char* lptr_t;

#define SQRT_LOG2E 1.2011224087864498f
#define LN2F 0.6931471805599453f
// log2(1+u) ~= u*(QC0 + QC1*u) on [0,1]
#define QC0 1.33985f
#define QC1 (-0.33985f)

#if __has_builtin(__builtin_amdgcn_exp2f)
#define EXP2F(x) __builtin_amdgcn_exp2f(x)
#else
#define EXP2F(x) exp2f(x)
#endif

// compiler memory-fence around raw barrier (builtin may be IntrNoMem)
#define BARRIER() do { asm volatile("" ::: "memory"); \
                       __builtin_amdgcn_s_barrier();  \
                       asm volatile("" ::: "memory"); } while (0)

__device__ __forceinline__ unsigned short f2bf(float f) {
  unsigned int u = __float_as_uint(f);
  u += 0x7fffu + ((u >> 16) & 1u);  // round-to-nearest-even
  return (unsigned short)(u >> 16);
}

__device__ __forceinline__ void tri_decode(int g, int& tr, int& tc) {
  int r = (int)((2 * NTILE + 1 -
                 sqrtf((float)((2 * NTILE + 1) * (2 * NTILE + 1)) - 8.0f * (float)g)) * 0.5f);
  while (r * NTILE - r * (r - 1) / 2 > g) --r;
  while ((r + 1) * NTILE - (r + 1) * r / 2 <= g) ++r;
  tr = r;
  tc = r + (g - (r * NTILE - r * (r - 1) / 2));
}

__global__ void cast_kernel(const float* __restrict__ in, unsigned short* __restrict__ out,
                            float* __restrict__ accum) {
  int i = blockIdx.x * blockDim.x + threadIdx.x;
  if (i == 0) accum[0] = 0.f;  // stream-ordered before loss kernel
  float4 v = reinterpret_cast<const float4*>(in)[i];
  ushort4 o;
  o.x = f2bf(v.x * SQRT_LOG2E); o.y = f2bf(v.y * SQRT_LOG2E);
  o.z = f2bf(v.z * SQRT_LOG2E); o.w = f2bf(v.w * SQRT_LOG2E);
  reinterpret_cast<ushort4*>(out)[i] = o;
}

// Swizzle involution: physical LDS byte p holds logical byte p^(((p>>8)&7)<<4);
// read side applies the same XOR (bits 4..6, below the 256B row stride).

__global__ __launch_bounds__(512, 2) void loss_persist(const unsigned short* __restrict__ ebf,
                                                       float* __restrict__ accum) {
  __shared__ alignas(16) unsigned short lds[2][2][128 * 128];  // [buf][A/B], 128 KiB
  __shared__ float red[8];
  const int tid = threadIdx.x;
  const int p = blockIdx.x;
  const int nt = (NTRI - 1 - p) / PBLOCKS + 1;  // 33 for p<64, else 32

  const int wid = tid >> 6;
  const int lane = tid & 63;
  const int wm = wid >> 2, wn = wid & 3;  // 2x4 waves: 64x32 output each
  const int lrow = lane & 15;
  const int kgrp = lane >> 4;

  // ---- stage tile g's A,B slabs into lds[buf] (8 global_load_lds / thread)
  auto stage = [&](int g, int buf) {
    int tr, tc;
    tri_decode(g, tr, tc);
    const unsigned char* sA = (const unsigned char*)ebf + (size_t)tr * 32768;
    const unsigned char* sB = (const unsigned char*)ebf + (size_t)tc * 32768;
#pragma unroll
    for (int it = 0; it < 4; ++it) {
      int pp = (it * 512 + tid) * 16;
      int gg = pp ^ (((pp >> 8) & 7) << 4);
      __builtin_amdgcn_global_load_lds((gptr_t)(sA + gg),
                                       (lptr_t)((unsigned char*)lds[buf][0] + pp), 16, 0, 0);
      __builtin_amdgcn_global_load_lds((gptr_t)(sB + gg),
                                       (lptr_t)((unsigned char*)lds[buf][1] + pp), 16, 0, 0);
    }
  };

  // ---- compute tile g from lds[buf]; returns this thread's weighted sum
  auto compute = [&](int g, int buf) -> float {
    int tr, tc;
    tri_decode(g, tr, tc);
    const unsigned char* As = (const unsigned char*)lds[buf][0];
    const unsigned char* Bs = (const unsigned char*)lds[buf][1];

    f32x4 acc[4][2];
#pragma unroll
    for (int a = 0; a < 4; ++a)
#pragma unroll
      for (int c = 0; c < 2; ++c) acc[a][c] = (f32x4){0.f, 0.f, 0.f, 0.f};

#pragma unroll
    for (int ks = 0; ks < 4; ++ks) {  // K = 128 = 4 * 32
      bf16x8 af[4], bfr[2];
#pragma unroll
      for (int f = 0; f < 4; ++f) {
        int ar = wm * 64 + f * 16 + lrow;
        int ab = (ar * 256 + ks * 64 + kgrp * 16) ^ ((ar & 7) << 4);
        af[f] = *reinterpret_cast<const bf16x8*>(As + ab);
      }
#pragma unroll
      for (int f = 0; f < 2; ++f) {
        int br = wn * 32 + f * 16 + lrow;
        int bb = (br * 256 + ks * 64 + kgrp * 16) ^ ((br & 7) << 4);
        bfr[f] = *reinterpret_cast<const bf16x8*>(Bs + bb);
      }
#pragma unroll
      for (int fm = 0; fm < 4; ++fm)
#pragma unroll
        for (int fn = 0; fn < 2; ++fn)
          acc[fm][fn] = __builtin_amdgcn_mfma_f32_16x16x32_bf16(af[fm], bfr[fn], acc[fm][fn], 0, 0, 0);
    }

    // epilogue, log2 domain. C/D layout: col=lane&15, row=(lane>>4)*4+reg.
    float sm = 0.f, sp = 0.f;
    if (tr == tc) {
#pragma unroll
      for (int fm = 0; fm < 4; ++fm)
#pragma unroll
        for (int fn = 0; fn < 2; ++fn)
#pragma unroll
          for (int r = 0; r < 4; ++r) {
            float v = acc[fm][fn][r];
            int il = wm * 64 + fm * 16 + kgrp * 4 + r;
            int jl = wn * 32 + fn * 16 + lrow;
            if (il == jl) v = -v;
            sm += fmaxf(v, 0.f);
            float u = EXP2F(-fabsf(v));
            sp = fmaf(u, fmaf(u, QC1, QC0), sp);
          }
      return sm + sp;
    } else {
#pragma unroll
      for (int fm = 0; fm < 4; ++fm)
#pragma unroll
        for (int fn = 0; fn < 2; ++fn)
#pragma unroll
          for (int r = 0; r < 4; ++r) {
            float v = acc[fm][fn][r];
            sm += fmaxf(v, 0.f);
            float u = EXP2F(-fabsf(v));
            sp = fmaf(u, fmaf(u, QC1, QC0), sp);
          }
      return 2.f * (sm + sp);  // symmetric twin tile
    }
  };

  // ---- pipelined tile loop: stage(t+1) in flight across compute(t) ----
  float total = 0.f;
  int buf = 0;
  stage(p, 0);
  for (int i = 0; i < nt - 1; ++i) {
    stage(p + (i + 1) * PBLOCKS, buf ^ 1);       // 8 more loads in flight
    asm volatile("s_waitcnt vmcnt(8)" ::: "memory");  // tile i's 8 landed
    BARRIER();                                    // all waves' stage visible
    total += compute(p + i * PBLOCKS, buf);
    BARRIER();                                    // reads done before overwrite
    buf ^= 1;
  }
  asm volatile("s_waitcnt vmcnt(0)" ::: "memory");
  BARRIER();
  total += compute(p + (nt - 1) * PBLOCKS, buf);

  // ---- block reduction, one atomic ----
#pragma unroll
  for (int off = 32; off > 0; off >>= 1) total += __shfl_down(total, off);
  BARRIER();  // lds buffers no longer needed; red[] reuse safe
  if (lane == 0) red[wid] = total;
  __syncthreads();
  if (tid == 0) {
    float t = red[0] + red[1] + red[2] + red[3] + red[4] + red[5] + red[6] + red[7];
    atomicAdd(accum, t);
  }
}

// fallback (ws too small for bf16 copy): round-6-style 2-phase, fp32 input
__global__ __launch_bounds__(512, 2) void loss_fallback(const float* __restrict__ src,
                                                        float* __restrict__ accum) {
  const int b = blockIdx.x;
  int tr, tc;
  tri_decode(b, tr, tc);

  __shared__ alignas(16) unsigned short As[128 * 128];
  __shared__ alignas(16) unsigned short Bs[128 * 128];
  __shared__ float red[8];
  const int tid = threadIdx.x;

  const float4* srcA4 = (const float4*)(src + (size_t)tr * 16384);
  const float4* srcB4 = (const float4*)(src + (size_t)tc * 16384);
#pragma unroll
  for (int it = 0; it < 8; ++it) {
    int idx = it * 512 + tid;
    int L = idx * 8;
    int swz = L ^ (((L >> 8) & 7) << 4);
    float4 a = srcA4[idx];
    ushort4 oa = {f2bf(a.x * SQRT_LOG2E), f2bf(a.y * SQRT_LOG2E),
                  f2bf(a.z * SQRT_LOG2E), f2bf(a.w * SQRT_LOG2E)};
    *reinterpret_cast<ushort4*>((unsigned char*)As + swz) = oa;
    float4 bb = srcB4[idx];
    ushort4 ob = {f2bf(bb.x * SQRT_LOG2E), f2bf(bb.y * SQRT_LOG2E),
                  f2bf(bb.z * SQRT_LOG2E), f2bf(bb.w * SQRT_LOG2E)};
    *reinterpret_cast<ushort4*>((unsigned char*)Bs + swz) = ob;
  }
  __syncthreads();

  const int wid = tid >> 6;
  const int lane = tid & 63;
  const int wm = wid >> 2, wn = wid & 3;
  const int lrow = lane & 15;
  const int kgrp = lane >> 4;

  f32x4 acc[4][2];
#pragma unroll
  for (int a = 0; a < 4; ++a)
#pragma unroll
    for (int c = 0; c < 2; ++c) acc[a][c] = (f32x4){0.f, 0.f, 0.f, 0.f};

#pragma unroll
  for (int ks = 0; ks < 4; ++ks) {
    bf16x8 af[4], bfr[2];
#pragma unroll
    for (int f = 0; f < 4; ++f) {
      int ar = wm * 64 + f * 16 + lrow;
      int ab = (ar * 256 + ks * 64 + kgrp * 16) ^ ((ar & 7) << 4);
      af[f] = *reinterpret_cast<const bf16x8*>((const unsigned char*)As + ab);
    }
#pragma unroll
    for (int f = 0; f < 2; ++f) {
      int br = wn * 32 + f * 16 + lrow;
      int bb = (br * 256 + ks * 64 + kgrp * 16) ^ ((br & 7) << 4);
      bfr[f] = *reinterpret_cast<const bf16x8*>((const unsigned char*)Bs + bb);
    }
#pragma unroll
    for (int fm = 0; fm < 4; ++fm)
#pragma unroll
      for (int fn = 0; fn < 2; ++fn)
        acc[fm][fn] = __builtin_amdgcn_mfma_f32_16x16x32_bf16(af[fm], bfr[fn], acc[fm][fn], 0, 0, 0);
  }

  float sm = 0.f, sp = 0.f;
  if (tr == tc) {
#pragma unroll
    for (int fm = 0; fm < 4; ++fm)
#pragma unroll
      for (int fn = 0; fn < 2; ++fn)
#pragma unroll
        for (int r = 0; r < 4; ++r) {
          float v = acc[fm][fn][r];
          int il = wm * 64 + fm * 16 + kgrp * 4 + r;
          int jl = wn * 32 + fn * 16 + lrow;
          if (il == jl) v = -v;
          sm += fmaxf(v, 0.f);
          float u = EXP2F(-fabsf(v));
          sp = fmaf(u, fmaf(u, QC1, QC0), sp);
        }
  } else {
#pragma unroll
    for (int fm = 0; fm < 4; ++fm)
#pragma unroll
      for (int fn = 0; fn < 2; ++fn)
#pragma unroll
        for (int r = 0; r < 4; ++r) {
          float v = acc[fm][fn][r];
          sm += fmaxf(v, 0.f);
          float u = EXP2F(-fabsf(v));
          sp = fmaf(u, fmaf(u, QC1, QC0), sp);
        }
    sm *= 2.f;
    sp *= 2.f;
  }

  float lsum = sm + sp;
#pragma unroll
  for (int off = 32; off > 0; off >>= 1) lsum += __shfl_down(lsum, off);
  if (lane == 0) red[wid] = lsum;
  __syncthreads();
  if (tid == 0) {
    float t = red[0] + red[1] + red[2] + red[3] + red[4] + red[5] + red[6] + red[7];
    atomicAdd(accum, t);
  }
}

__global__ void finalize_kernel(const float* __restrict__ accum, float* __restrict__ out) {
  // accum is in log2 units: loss = ln2 * (accum/N + 1)
  out[0] = LN2F * (accum[0] * (1.0f / (float)N_DOCS) + 1.0f);
}

extern "C" void kernel_launch(void* const* d_in, const int* in_sizes, int n_in,
                              void* d_out, int out_size, void* d_ws, size_t ws_size,
                              hipStream_t stream) {
  const float* E = (const float*)d_in[0];
  float* out = (float*)d_out;
  float* accum = (float*)d_ws;  // 4 B

  const size_t need = 256 + (size_t)N_DOCS * DIM * sizeof(unsigned short);  // ~4 MiB
  if (ws_size >= need) {
    unsigned short* ebf = (unsigned short*)((char*)d_ws + 256);
    cast_kernel<<<(N_DOCS * DIM / 4) / 256, 256, 0, stream>>>(E, ebf, accum);
    loss_persist<<<PBLOCKS, 512, 0, stream>>>(ebf, accum);
  } else {
    (void)hipMemsetAsync(accum, 0, sizeof(float), stream);
    loss_fallback<<<NTRI, 512, 0, stream>>>(E, accum);
  }
  finalize_kernel<<<1, 1, 0, stream>>>(accum, out);
}

// Round 11
// 106.581 us; speedup vs baseline: 6.7391x; 1.2690x over previous
//
#include <hip/hip_runtime.h>
#include <hip/hip_bf16.h>

// loss = (1/N) * [ sum_i softplus(-s_ii) + sum_{i!=j} softplus(s_ij) ] + ln2
// S = E E^T, N=16384, D=128.
// E pre-scaled by sqrt(log2e), cast to fp8 e4m3 (OCP, HW cvt) in a k-tiled
// layout; scores come out in log2 domain: softplus*log2e = max(v,0) +
// log2(1+2^-|v|) ~= max(v,0) + u*(QC0+QC1*u), u = 2^-|v|.
// PERSISTENT + PIPELINED: 512 blocks (2/CU, 64KiB LDS dbuf -> 16 waves/CU),
// each walks ~16 triangular 128x128 tiles; cross-tile double-buffered
// global_load_lds staging (pure linear copy -- conflict-free layout is baked
// into the fp8 intermediate by the cast kernel), counted vmcnt(4), raw
// s_barrier, mfma_f32_16x16x32_fp8_fp8, fused epilogue, 1 atomic/block.
// fp8 tiled layout per 128-row slab (16KB): element (r,k): kb=k/8, g=kb&3,
// s=kb>>2, P2=g*2+(s>>1), w=s&1 -> byte P2*2048 + r*16 + w*8 + (k&7).
// Read side: b128 at (kgrp*2+ks2)*2048 + row*16 gives the lane's 8 fp8 for
// ks=2*ks2 (low long) and ks=2*ks2+1 (high long).

#define N_DOCS 16384
#define DIM 128
#define NTILE 128                      // N_DOCS / 128
#define NTRI (NTILE * (NTILE + 1) / 2) // 8256
#define PBLOCKS 512                    // persistent blocks, 2 per CU

typedef __attribute__((ext_vector_type(4))) float f32x4;
typedef __attribute__((ext_vector_type(8))) __bf16 bf16x8;   // fallback path
typedef __attribute__((ext_vector_type(2))) long longx2;

typedef const __attribute__((address_space(1))) unsigned char* gptr_t;
typedef __attribute__((address_space(3))) unsigned char* lptr_t;

#define SQRT_LOG2E 1.2011224087864498f
#define LN2F 0.6931471805599453f
// log2(1+u) ~= u*(QC0 + QC1*u) on [0,1]
#define QC0 1.33985f
#define QC1 (-0.33985f)

#if __has_builtin(__builtin_amdgcn_exp2f)
#define EXP2F(x) __builtin_amdgcn_exp2f(x)
#else
#define EXP2F(x) exp2f(x)
#endif

// compiler memory-fence around raw barrier
#define BARRIER() do { asm volatile("" ::: "memory"); \
                       __builtin_amdgcn_s_barrier();  \
                       asm volatile("" ::: "memory"); } while (0)

__device__ __forceinline__ unsigned short f2bf(float f) {
  unsigned int u = __float_as_uint(f);
  u += 0x7fffu + ((u >> 16) & 1u);
  return (unsigned short)(u >> 16);
}

#if __has_builtin(__builtin_amdgcn_cvt_pk_fp8_f32)
#define HAVE_CVT_FP8 1
#else
// manual OCP e4m3fn RNE fallback
__device__ __forceinline__ unsigned char f2e4m3(float x) {
  unsigned int u = __float_as_uint(x);
  unsigned char sgn = (unsigned char)((u >> 31) << 7);
  float ax = fabsf(x);
  if (!(ax < 464.f)) return sgn | 0x7E;  // saturate
  unsigned int ua = u & 0x7FFFFFFFu;
  int e = (int)(ua >> 23) - 127;
  if (e < -6) {
    float q = rintf(ax * 512.f);  // subnormal step 2^-9
    return sgn | (unsigned char)q;
  }
  unsigned int mant = ua & 0x7FFFFFu;
  unsigned int keep = mant >> 20;
  unsigned int rest = mant & 0xFFFFFu;
  keep += (rest > 0x80000u) || (rest == 0x80000u && (keep & 1u));
  unsigned int ee = (unsigned int)(e + 7);
  if (keep == 8u) { keep = 0u; ee++; }
  if (ee >= 16u) return sgn | 0x7E;
  return sgn | (unsigned char)((ee << 3) | keep);
}
#endif

__device__ __forceinline__ void tri_decode(int g, int& tr, int& tc) {
  int r = (int)((2 * NTILE + 1 -
                 sqrtf((float)((2 * NTILE + 1) * (2 * NTILE + 1)) - 8.0f * (float)g)) * 0.5f);
  while (r * NTILE - r * (r - 1) / 2 > g) --r;
  while ((r + 1) * NTILE - (r + 1) * r / 2 <= g) ++r;
  tr = r;
  tc = r + (g - (r * NTILE - r * (r - 1) / 2));
}

// f32 -> scaled fp8, k-tiled layout. One thread = one (row, kb) = 8 elements.
__global__ void cast_kernel(const float* __restrict__ in, unsigned char* __restrict__ out,
                            float* __restrict__ accum) {
  int i = blockIdx.x * blockDim.x + threadIdx.x;  // [0, 262144)
  if (i == 0) accum[0] = 0.f;                      // stream-ordered before loss
  int row = i >> 4, kb = i & 15;
  const float4* p = reinterpret_cast<const float4*>(in + (size_t)row * 128 + kb * 8);
  float4 a = p[0], b = p[1];
  int w0, w1;
#ifdef HAVE_CVT_FP8
  w0 = __builtin_amdgcn_cvt_pk_fp8_f32(a.x * SQRT_LOG2E, a.y * SQRT_LOG2E, 0, false);
  w0 = __builtin_amdgcn_cvt_pk_fp8_f32(a.z * SQRT_LOG2E, a.w * SQRT_LOG2E, w0, true);
  w1 = __builtin_amdgcn_cvt_pk_fp8_f32(b.x * SQRT_LOG2E, b.y * SQRT_LOG2E, 0, false);
  w1 = __builtin_amdgcn_cvt_pk_fp8_f32(b.z * SQRT_LOG2E, b.w * SQRT_LOG2E, w1, true);
#else
  w0 = (int)f2e4m3(a.x * SQRT_LOG2E) | ((int)f2e4m3(a.y * SQRT_LOG2E) << 8) |
       ((int)f2e4m3(a.z * SQRT_LOG2E) << 16) | ((int)f2e4m3(a.w * SQRT_LOG2E) << 24);
  w1 = (int)f2e4m3(b.x * SQRT_LOG2E) | ((int)f2e4m3(b.y * SQRT_LOG2E) << 8) |
       ((int)f2e4m3(b.z * SQRT_LOG2E) << 16) | ((int)f2e4m3(b.w * SQRT_LOG2E) << 24);
#endif
  int slab = row >> 7, r = row & 127, g = kb & 3, s = kb >> 2;
  int off = slab * 16384 + (g * 2 + (s >> 1)) * 2048 + r * 16 + (s & 1) * 8;
  *reinterpret_cast<int2*>(out + off) = make_int2(w0, w1);
}

__global__ __launch_bounds__(512, 4) void loss_persist(const unsigned char* __restrict__ ef8,
                                                       float* __restrict__ accum) {
  __shared__ alignas(16) unsigned char lds[2][2][16384];  // [buf][A/B], 64 KiB
  __shared__ float red[8];
  const int tid = threadIdx.x;
  const int p = blockIdx.x;
  const int nt = (NTRI - 1 - p) / PBLOCKS + 1;  // 17 for p<64, else 16

  const int wid = tid >> 6;
  const int lane = tid & 63;
  const int wm = wid >> 2, wn = wid & 3;  // 2x4 waves: 64x32 output each
  const int lrow = lane & 15;
  const int kgrp = lane >> 4;

  // ---- stage tile g's A,B slabs (pure linear copy, 4 loads/thread) ----
  auto stage = [&](int g, int buf) {
    int tr, tc;
    tri_decode(g, tr, tc);
    const unsigned char* sA = ef8 + (size_t)tr * 16384;
    const unsigned char* sB = ef8 + (size_t)tc * 16384;
#pragma unroll
    for (int it = 0; it < 2; ++it) {
      int pp = (it * 512 + tid) * 16;
      __builtin_amdgcn_global_load_lds((gptr_t)(sA + pp),
                                       (lptr_t)((unsigned char*)lds[buf][0] + pp), 16, 0, 0);
      __builtin_amdgcn_global_load_lds((gptr_t)(sB + pp),
                                       (lptr_t)((unsigned char*)lds[buf][1] + pp), 16, 0, 0);
    }
  };

  // ---- compute tile g from lds[buf] ----
  auto compute = [&](int g, int buf) -> float {
    int tr, tc;
    tri_decode(g, tr, tc);
    const unsigned char* As = (const unsigned char*)lds[buf][0];
    const unsigned char* Bs = (const unsigned char*)lds[buf][1];

    f32x4 acc[4][2];
#pragma unroll
    for (int a = 0; a < 4; ++a)
#pragma unroll
      for (int c = 0; c < 2; ++c) acc[a][c] = (f32x4){0.f, 0.f, 0.f, 0.f};

#pragma unroll
    for (int ks2 = 0; ks2 < 2; ++ks2) {  // each iter covers K-slices 2*ks2, 2*ks2+1
      longx2 af[4], bf[2];
      const int pbase = (kgrp * 2 + ks2) * 2048;
#pragma unroll
      for (int f = 0; f < 4; ++f) {
        int ar = wm * 64 + f * 16 + lrow;
        af[f] = *reinterpret_cast<const longx2*>(As + pbase + ar * 16);
      }
#pragma unroll
      for (int f = 0; f < 2; ++f) {
        int br = wn * 32 + f * 16 + lrow;
        bf[f] = *reinterpret_cast<const longx2*>(Bs + pbase + br * 16);
      }
#pragma unroll
      for (int fm = 0; fm < 4; ++fm)
#pragma unroll
        for (int fn = 0; fn < 2; ++fn) {
          acc[fm][fn] = __builtin_amdgcn_mfma_f32_16x16x32_fp8_fp8(af[fm].x, bf[fn].x,
                                                                   acc[fm][fn], 0, 0, 0);
          acc[fm][fn] = __builtin_amdgcn_mfma_f32_16x16x32_fp8_fp8(af[fm].y, bf[fn].y,
                                                                   acc[fm][fn], 0, 0, 0);
        }
    }

    // epilogue, log2 domain. C/D layout: col=lane&15, row=(lane>>4)*4+reg.
    float sm = 0.f, sp = 0.f;
    if (tr == tc) {
#pragma unroll
      for (int fm = 0; fm < 4; ++fm)
#pragma unroll
        for (int fn = 0; fn < 2; ++fn)
#pragma unroll
          for (int r = 0; r < 4; ++r) {
            float v = acc[fm][fn][r];
            int il = wm * 64 + fm * 16 + kgrp * 4 + r;
            int jl = wn * 32 + fn * 16 + lrow;
            if (il == jl) v = -v;
            sm += fmaxf(v, 0.f);
            float u = EXP2F(-fabsf(v));
            sp = fmaf(u, fmaf(u, QC1, QC0), sp);
          }
      return sm + sp;
    } else {
#pragma unroll
      for (int fm = 0; fm < 4; ++fm)
#pragma unroll
        for (int fn = 0; fn < 2; ++fn)
#pragma unroll
          for (int r = 0; r < 4; ++r) {
            float v = acc[fm][fn][r];
            sm += fmaxf(v, 0.f);
            float u = EXP2F(-fabsf(v));
            sp = fmaf(u, fmaf(u, QC1, QC0), sp);
          }
      return 2.f * (sm + sp);  // symmetric twin tile
    }
  };

  // ---- pipelined tile loop: stage(t+1) stays in flight across compute(t) ----
  float total = 0.f;
  int buf = 0;
  stage(p, 0);
  for (int i = 0; i < nt - 1; ++i) {
    stage(p + (i + 1) * PBLOCKS, buf ^ 1);            // 4 more loads in flight
    asm volatile("s_waitcnt vmcnt(4)" ::: "memory");  // tile i's 4 landed
    BARRIER();                                        // all waves' stage visible
    total += compute(p + i * PBLOCKS, buf);
    BARRIER();                                        // reads done before overwrite
    buf ^= 1;
  }
  asm volatile("s_waitcnt vmcnt(0)" ::: "memory");
  BARRIER();
  total += compute(p + (nt - 1) * PBLOCKS, buf);

  // ---- block reduction, one atomic ----
#pragma unroll
  for (int off = 32; off > 0; off >>= 1) total += __shfl_down(total, off);
  if (lane == 0) red[wid] = total;
  __syncthreads();
  if (tid == 0) {
    float t = red[0] + red[1] + red[2] + red[3] + red[4] + red[5] + red[6] + red[7];
    atomicAdd(accum, t);
  }
}

// fallback (ws too small): bf16-from-fp32 2-phase per-tile grid (round-10)
__global__ __launch_bounds__(512, 2) void loss_fallback(const float* __restrict__ src,
                                                        float* __restrict__ accum) {
  const int b = blockIdx.x;
  int tr, tc;
  tri_decode(b, tr, tc);

  __shared__ alignas(16) unsigned short As[128 * 128];
  __shared__ alignas(16) unsigned short Bs[128 * 128];
  __shared__ float red[8];
  const int tid = threadIdx.x;

  const float4* srcA4 = (const float4*)(src + (size_t)tr * 16384);
  const float4* srcB4 = (const float4*)(src + (size_t)tc * 16384);
#pragma unroll
  for (int it = 0; it < 8; ++it) {
    int idx = it * 512 + tid;
    int L = idx * 8;
    int swz = L ^ (((L >> 8) & 7) << 4);
    float4 a = srcA4[idx];
    ushort4 oa = {f2bf(a.x * SQRT_LOG2E), f2bf(a.y * SQRT_LOG2E),
                  f2bf(a.z * SQRT_LOG2E), f2bf(a.w * SQRT_LOG2E)};
    *reinterpret_cast<ushort4*>((unsigned char*)As + swz) = oa;
    float4 bb = srcB4[idx];
    ushort4 ob = {f2bf(bb.x * SQRT_LOG2E), f2bf(bb.y * SQRT_LOG2E),
                  f2bf(bb.z * SQRT_LOG2E), f2bf(bb.w * SQRT_LOG2E)};
    *reinterpret_cast<ushort4*>((unsigned char*)Bs + swz) = ob;
  }
  __syncthreads();

  const int wid = tid >> 6;
  const int lane = tid & 63;
  const int wm = wid >> 2, wn = wid & 3;
  const int lrow = lane & 15;
  const int kgrp = lane >> 4;

  f32x4 acc[4][2];
#pragma unroll
  for (int a = 0; a < 4; ++a)
#pragma unroll
    for (int c = 0; c < 2; ++c) acc[a][c] = (f32x4){0.f, 0.f, 0.f, 0.f};

#pragma unroll
  for (int ks = 0; ks < 4; ++ks) {
    bf16x8 af[4], bfr[2];
#pragma unroll
    for (int f = 0; f < 4; ++f) {
      int ar = wm * 64 + f * 16 + lrow;
      int ab = (ar * 256 + ks * 64 + kgrp * 16) ^ ((ar & 7) << 4);
      af[f] = *reinterpret_cast<const bf16x8*>((const unsigned char*)As + ab);
    }
#pragma unroll
    for (int f = 0; f < 2; ++f) {
      int br = wn * 32 + f * 16 + lrow;
      int bb = (br * 256 + ks * 64 + kgrp * 16) ^ ((br & 7) << 4);
      bfr[f] = *reinterpret_cast<const bf16x8*>((const unsigned char*)Bs + bb);
    }
#pragma unroll
    for (int fm = 0; fm < 4; ++fm)
#pragma unroll
      for (int fn = 0; fn < 2; ++fn)
        acc[fm][fn] = __builtin_amdgcn_mfma_f32_16x16x32_bf16(af[fm], bfr[fn], acc[fm][fn], 0, 0, 0);
  }

  float sm = 0.f, sp = 0.f;
  if (tr == tc) {
#pragma unroll
    for (int fm = 0; fm < 4; ++fm)
#pragma unroll
      for (int fn = 0; fn < 2; ++fn)
#pragma unroll
        for (int r = 0; r < 4; ++r) {
          float v = acc[fm][fn][r];
          int il = wm * 64 + fm * 16 + kgrp * 4 + r;
          int jl = wn * 32 + fn * 16 + lrow;
          if (il == jl) v = -v;
          sm += fmaxf(v, 0.f);
          float u = EXP2F(-fabsf(v));
          sp = fmaf(u, fmaf(u, QC1, QC0), sp);
        }
  } else {
#pragma unroll
    for (int fm = 0; fm < 4; ++fm)
#pragma unroll
      for (int fn = 0; fn < 2; ++fn)
#pragma unroll
        for (int r = 0; r < 4; ++r) {
          float v = acc[fm][fn][r];
          sm += fmaxf(v, 0.f);
          float u = EXP2F(-fabsf(v));
          sp = fmaf(u, fmaf(u, QC1, QC0), sp);
        }
    sm *= 2.f;
    sp *= 2.f;
  }

  float lsum = sm + sp;
#pragma unroll
  for (int off = 32; off > 0; off >>= 1) lsum += __shfl_down(lsum, off);
  if (lane == 0) red[wid] = lsum;
  __syncthreads();
  if (tid == 0) {
    float t = red[0] + red[1] + red[2] + red[3] + red[4] + red[5] + red[6] + red[7];
    atomicAdd(accum, t);
  }
}

__global__ void finalize_kernel(const float* __restrict__ accum, float* __restrict__ out) {
  out[0] = LN2F * (accum[0] * (1.0f / (float)N_DOCS) + 1.0f);  // accum in log2 units
}

extern "C" void kernel_launch(void* const* d_in, const int* in_sizes, int n_in,
                              void* d_out, int out_size, void* d_ws, size_t ws_size,
                              hipStream_t stream) {
  const float* E = (const float*)d_in[0];
  float* out = (float*)d_out;
  float* accum = (float*)d_ws;  // 4 B

  const size_t need = 256 + (size_t)N_DOCS * DIM;  // ~2 MiB fp8 copy
  if (ws_size >= need) {
    unsigned char* ef8 = (unsigned char*)d_ws + 256;
    cast_kernel<<<(N_DOCS * (DIM / 8)) / 256, 256, 0, stream>>>(E, ef8, accum);
    loss_persist<<<PBLOCKS, 512, 0, stream>>>(ef8, accum);
  } else {
    (void)hipMemsetAsync(accum, 0, sizeof(float), stream);
    loss_fallback<<<NTRI, 512, 0, stream>>>(E, accum);
  }
  finalize_kernel<<<1, 1, 0, stream>>>(accum, out);
}